// Round 3
// baseline (464.689 us; speedup 1.0000x reference)
//
#include <hip/hip_runtime.h>
#include <hip/hip_bf16.h>
#include <math.h>

// Problem constants (fixed by the reference setup_inputs)
#define BB 32
#define PP 24564
#define OO 16
#define CC 81
#define BP (BB * PP)
#define CHUNK 1024   // priors per k_match_a block; ceil(PP/CHUNK)=24 chunks

typedef unsigned long long ull;

__device__ __forceinline__ float sl1(float x) {
    float ax = fabsf(x);
    return ax < 1.0f ? 0.5f * ax * ax : ax - 0.5f;
}

// ---------------------------------------------------------------------------
// K1: slim matcher. Only computes per-(batch,truth) best prior via packed-key
// max: key = (iou_bits << 32) | (0xFFFFFFFF - p) -> max iou, tie: smallest p.
// Per-prior best-truth is recomputed inside k_ce (16 IoUs/row, trivial VALU),
// so no bto/bti global round-trip. Wave shfl_xor butterfly, 16 global
// atomicMax per block.
// ---------------------------------------------------------------------------
__global__ __launch_bounds__(256) void k_match_a(
        const float* __restrict__ priors, const float* __restrict__ truths,
        ull* __restrict__ best_prior /* [BB][OO], pre-zeroed */) {
    const int b = blockIdx.y;
    const int p0 = blockIdx.x * CHUNK;
    const int tid = threadIdx.x;
    __shared__ float tr[OO][4];
    __shared__ float tarea[OO];
    __shared__ ull red[4][OO];
    if (tid < OO * 4) ((float*)tr)[tid] = truths[b * OO * 4 + tid];
    __syncthreads();
    if (tid < OO) tarea[tid] = (tr[tid][2] - tr[tid][0]) * (tr[tid][3] - tr[tid][1]);
    __syncthreads();

    float bpv[OO];
    int bpi[OO];
#pragma unroll
    for (int o = 0; o < OO; o++) { bpv[o] = -1.0f; bpi[o] = -1; }

    const int pend = (p0 + CHUNK < PP) ? p0 + CHUNK : PP;
    for (int p = p0 + tid; p < pend; p += 256) {
        const float4 pr = ((const float4*)priors)[p];
        const float x1 = pr.x - pr.z * 0.5f, y1 = pr.y - pr.w * 0.5f;
        const float x2 = pr.x + pr.z * 0.5f, y2 = pr.y + pr.w * 0.5f;
        const float parea = (x2 - x1) * (y2 - y1);
#pragma unroll
        for (int o = 0; o < OO; o++) {
            const float lx = fmaxf(tr[o][0], x1), ly = fmaxf(tr[o][1], y1);
            const float rx = fminf(tr[o][2], x2), ry = fminf(tr[o][3], y2);
            const float iw = fmaxf(rx - lx, 0.0f), ih = fmaxf(ry - ly, 0.0f);
            const float inter = iw * ih;
            const float iou = inter / (tarea[o] + parea - inter);
            if (iou > bpv[o]) { bpv[o] = iou; bpi[o] = p; }    // p ascending per thread
        }
    }

    // wave-level butterfly max-reduce of the packed key, per truth o
    const int wave = tid >> 6;
    const int lane = tid & 63;
#pragma unroll
    for (int o = 0; o < OO; o++) {
        ull key = (bpi[o] >= 0)
            ? (((ull)__float_as_uint(bpv[o]) << 32) |
               (ull)(0xFFFFFFFFu - (unsigned)bpi[o]))
            : 0ull;
#pragma unroll
        for (int d = 32; d; d >>= 1) {
            const ull other = __shfl_xor(key, d);
            key = (other > key) ? other : key;
        }
        if (lane == 0) red[wave][o] = key;
    }
    __syncthreads();
    if (tid < OO) {
        const ull k0 = red[0][tid], k1 = red[1][tid];
        const ull k2 = red[2][tid], k3 = red[3][tid];
        ull m = k0 > k1 ? k0 : k1;
        const ull m2 = k2 > k3 ? k2 : k3;
        m = m > m2 ? m : m2;
        if (m != 0ull) atomicMax(&best_prior[b * OO + tid], m);
    }
}

// ---------------------------------------------------------------------------
// K2: tile of 64 rows per block, conf staged through LDS with coalesced
// float4 loads. LSE by 4 threads/row; epilogue by wave 0 (64 threads), which
// recomputes its rows' best-truth match (16 IoUs) and applies the forced
// best-prior override from a 16-entry LDS table (ascending-o loop = numpy
// last-writer-wins). Positive contributions wave-reduced; lane 0 issues <=5
// atomics into striped accumulators.
// ---------------------------------------------------------------------------
__global__ __launch_bounds__(256) void k_ce(
        const float* __restrict__ conf, const float* __restrict__ obj,
        const float* __restrict__ loc, const float* __restrict__ priors,
        const float* __restrict__ truths, const int* __restrict__ labels,
        const ull* __restrict__ best_prior,
        float* __restrict__ mining_obj, float* __restrict__ mining_c,
        int* __restrict__ num_posS /* [8][BB] */,
        float* __restrict__ accS  /* [64][32] */) {
    const int tid = threadIdx.x;
    const int row0 = blockIdx.x * 64;            // BP == 64 * gridDim.x exactly
    const int b0 = row0 / PP;
    __shared__ float sconf[64 * CC];             // 20736 B
    __shared__ float slse[64];
    __shared__ float4 s_tr[2][OO];
    __shared__ float  s_ta[2][OO];
    __shared__ int    s_lb[2][OO];
    __shared__ unsigned s_fp[2][OO];

    // per-batch tables (block can straddle one batch boundary; last batch
    // never straddles, so b0+1 <= 31 whenever nb == 2)
    const int nb = ((row0 - b0 * PP) + 64 > PP) ? 2 : 1;
    if (tid < nb * OO) {
        const int bb = tid >> 4, o = tid & 15;
        const float4 t = ((const float4*)truths)[(b0 + bb) * OO + o];
        s_tr[bb][o] = t;
        s_ta[bb][o] = (t.z - t.x) * (t.w - t.y);
        s_lb[bb][o] = labels[(b0 + bb) * OO + o];
        s_fp[bb][o] = 0xFFFFFFFFu -
            (unsigned)(best_prior[(b0 + bb) * OO + o] & 0xFFFFFFFFull);
    }

    const float4* src = (const float4*)(conf + (size_t)row0 * CC);
    float4* dst = (float4*)sconf;
    for (int i = tid; i < (64 * CC) / 4; i += 256) dst[i] = src[i];
    __syncthreads();

    const int r = tid >> 2;
    const int part = tid & 3;
    const float* rowp = sconf + r * CC;
    const int c0 = part * 20;
    const int c1 = (part == 3) ? CC : c0 + 20;   // 20,20,20,21
    float m = -INFINITY;
    for (int c = c0; c < c1; c++) m = fmaxf(m, rowp[c]);
    m = fmaxf(m, __shfl_xor(m, 1));
    m = fmaxf(m, __shfl_xor(m, 2));
    float s = 0.0f;
    for (int c = c0; c < c1; c++) s += __expf(rowp[c] - m);
    s += __shfl_xor(s, 1);
    s += __shfl_xor(s, 2);
    if (part == 0) slse[r] = m + __logf(s);
    __syncthreads();

    if (tid < 64) {                              // exactly wave 0
        const int row = row0 + tid;
        const int b = row / PP;
        const int lb_i = b - b0;
        const int p = row - b * PP;

        // natural match: first-max over o (same semantics as old k_match_a)
        const float4 pr = ((const float4*)priors)[p];
        const float x1 = pr.x - pr.z * 0.5f, y1 = pr.y - pr.w * 0.5f;
        const float x2 = pr.x + pr.z * 0.5f, y2 = pr.y + pr.w * 0.5f;
        const float parea = (x2 - x1) * (y2 - y1);
        float best = -1.0f;
        int ti = 0;
#pragma unroll
        for (int o = 0; o < OO; o++) {
            const float4 t = s_tr[lb_i][o];
            const float lx = fmaxf(t.x, x1), ly = fmaxf(t.y, y1);
            const float rx = fminf(t.z, x2), ry = fminf(t.w, y2);
            const float iw = fmaxf(rx - lx, 0.0f), ih = fmaxf(ry - ly, 0.0f);
            const float inter = iw * ih;
            const float iou = inter / (s_ta[lb_i][o] + parea - inter);
            if (iou > best) { best = iou; ti = o; }
        }
        float ov = best;
        // forced best-prior override, ascending o = last-writer-wins
#pragma unroll
        for (int o = 0; o < OO; o++) {
            if (s_fp[lb_i][o] == (unsigned)p) { ti = o; ov = 2.0f; }
        }

        const int lbl = s_lb[lb_i][ti];
        const int tgt = (ov < 0.5f) ? 0 : lbl;
        const float ce_c = slse[tid] - sconf[tid * CC + tgt];

        const float2 o2 = ((const float2*)obj)[row];
        const float mo = fmaxf(o2.x, o2.y);
        const float lse_o = mo + __logf(__expf(o2.x - mo) + __expf(o2.y - mo));
        const bool pos = tgt > 0;
        const float ce_o = lse_o - (pos ? o2.y : o2.x);

        mining_c[row]   = pos ? 0.0f : ce_c;
        mining_obj[row] = pos ? 0.0f : ce_o;

        float my_l = 0.0f, my_co = 0.0f, my_cc = 0.0f;
        if (pos) {
            my_co = ce_o;
            my_cc = ce_c;
            const float4 t = s_tr[lb_i][ti];
            const float gcx = ((t.x + t.z) * 0.5f - pr.x) / (0.1f * pr.z);
            const float gcy = ((t.y + t.w) * 0.5f - pr.y) / (0.1f * pr.w);
            const float gw = logf((t.z - t.x) / pr.z) / 0.2f;
            const float gh = logf((t.w - t.y) / pr.w) / 0.2f;
            const float4 ld = ((const float4*)loc)[row];
            my_l = sl1(ld.x - gcx) + sl1(ld.y - gcy) +
                   sl1(ld.z - gw) + sl1(ld.w - gh);
        }

        // --- wave-level reduction: counts via ballot, sums via shfl tree ---
        const ull mpos = __ballot(pos);
        const ull mb1  = __ballot(b != b0);      // rows spilling into batch b0+1
#pragma unroll
        for (int d = 32; d; d >>= 1) {
            my_l  += __shfl_down(my_l,  d);
            my_co += __shfl_down(my_co, d);
            my_cc += __shfl_down(my_cc, d);
        }
        if (tid == 0 && mpos) {
            const int cnt0 = __popcll(mpos & ~mb1);
            const int cnt1 = __popcll(mpos &  mb1);
            int* nps = num_posS + (blockIdx.x & 7) * BB;
            if (cnt0) atomicAdd(&nps[b0], cnt0);
            if (cnt1) atomicAdd(&nps[b0 + 1], cnt1);
            float* slot = accS + (size_t)(blockIdx.x & 63) * 32;
            atomicAdd(slot + 0, my_l);
            atomicAdd(slot + 1, my_co);
            atomicAdd(slot + 2, my_cc);
        }
    }
}

// ---------------------------------------------------------------------------
// K3: top-k sum via 4-pass byte radix-select. 64 blocks: {obj,c} x 32 batches,
// 1024 threads. v3: per-wave privatized histograms (histw[16][256]) — pass 1
// concentrates ~24K elements into ONE bucket (CE values share exponent byte
// 0x40), which serialized as same-address LDS atomics on a shared histogram.
// ---------------------------------------------------------------------------
__global__ __launch_bounds__(1024) void k_select(
        const float* __restrict__ mining /* [2][B][P] */,
        const int* __restrict__ num_posS /* [8][BB] */,
        float* __restrict__ acc,
        int* __restrict__ n1_acc) {
    const int arr = blockIdx.x >> 5;  // 0 = obj, 1 = c
    const int b = blockIdx.x & 31;
    const int tid = threadIdx.x;
    const int wv = tid >> 6;
    const float* x = mining + ((size_t)arr * BB + b) * PP;
    int np = 0;
#pragma unroll
    for (int s = 0; s < 8; s++) np += num_posS[s * BB + b];
    long long k64 = 3LL * np;
    const int k = (int)(k64 < (long long)(PP - 1) ? k64 : (long long)(PP - 1));
    if (tid == 0 && arr == 0) atomicAdd(n1_acc, k);
    if (k <= 0) return;

    __shared__ unsigned histw[16][256];   // 16 KiB, per-wave privatized
    __shared__ unsigned hist[256];
    __shared__ unsigned s_prefix;
    __shared__ int s_krem;
    __shared__ float wsum[16];
    __shared__ unsigned wcnt[16];
    if (tid == 0) { s_prefix = 0u; s_krem = k; }

    for (int shift = 24; shift >= 0; shift -= 8) {
        __syncthreads();                       // prefix/krem from prev pass ready
        for (int i = tid; i < 16 * 256; i += 1024) ((unsigned*)histw)[i] = 0u;
        const unsigned prefix = s_prefix;
        const unsigned pmask = (shift == 24) ? 0u : (0xFFFFFFFFu << (shift + 8));
        __syncthreads();                       // histw zeroed
        for (int i = tid; i < PP; i += 1024) {
            const unsigned u = __float_as_uint(x[i]);
            if ((u & pmask) == prefix)
                atomicAdd(&histw[wv][(u >> shift) & 255u], 1u);
        }
        __syncthreads();
        if (tid < 256) {
            unsigned s = 0;
#pragma unroll
            for (int w = 0; w < 16; w++) s += histw[w][tid];
            hist[tid] = s;
        }
        __syncthreads();
        if (tid == 0) {
            const int krem = s_krem;
            unsigned cum = 0;
            int sel = 0;
            for (int byte = 255; byte >= 0; byte--) {
                const unsigned h = hist[byte];
                if (cum + h >= (unsigned)krem) { sel = byte; break; }
                cum += h;
            }
            s_krem = krem - (int)cum;
            s_prefix = prefix | ((unsigned)sel << shift);
        }
    }
    __syncthreads();

    const unsigned t = s_prefix;
    float lsum = 0.0f;
    unsigned lcnt = 0;
    for (int i = tid; i < PP; i += 1024) {
        const float v = x[i];
        if (__float_as_uint(v) > t) { lsum += v; lcnt++; }
    }
#pragma unroll
    for (int d = 32; d; d >>= 1) {
        lsum += __shfl_down(lsum, d);
        lcnt += __shfl_down(lcnt, d);
    }
    if ((tid & 63) == 0) { wsum[wv] = lsum; wcnt[wv] = lcnt; }
    __syncthreads();
    if (tid == 0) {
        float ts = 0.0f;
        unsigned tc = 0;
#pragma unroll
        for (int w = 0; w < 16; w++) { ts += wsum[w]; tc += wcnt[w]; }
        const float tsum = ts + (float)(k - (int)tc) * __uint_as_float(t);
        atomicAdd(&acc[3 + arr], tsum);
    }
}

// K4: final scalars. One wave; sums the striped accumulators.
__global__ void k_final(const float* __restrict__ acc,
                        const float* __restrict__ accS /* [64][32] */,
                        const int* __restrict__ num_posS /* [8][BB] = 256 ints */,
                        const int* __restrict__ n1_acc,
                        float* __restrict__ out) {
    const int t = threadIdx.x;   // 64 threads
    float sl = accS[t * 32 + 0];
    float so = accS[t * 32 + 1];
    float sc = accS[t * 32 + 2];
    int np = 0;
#pragma unroll
    for (int i = 0; i < 4; i++) np += num_posS[t + i * 64];
#pragma unroll
    for (int d = 32; d; d >>= 1) {
        sl += __shfl_down(sl, d);
        so += __shfl_down(so, d);
        sc += __shfl_down(sc, d);
        np += __shfl_down(np, d);
    }
    if (t == 0) {
        const float fN = (float)(np > 1 ? np : 1);
        const int n1 = *n1_acc;
        const float fN1 = (float)(n1 > 1 ? n1 : 1);
        out[0] = sl / fN;
        out[1] = (sc + acc[4]) / fN;
        out[2] = 0.4f * (so + acc[3]) / fN1;
    }
}

extern "C" void kernel_launch(void* const* d_in, const int* in_sizes, int n_in,
                              void* d_out, int out_size, void* d_ws, size_t ws_size,
                              hipStream_t stream) {
    const float* loc_data  = (const float*)d_in[0];
    const float* conf_data = (const float*)d_in[1];
    const float* obj_data  = (const float*)d_in[2];
    const float* priors    = (const float*)d_in[3];
    const float* truths    = (const float*)d_in[4];
    const int*   labels    = (const int*)d_in[5];
    float* out = (float*)d_out;

    // Workspace layout (float offsets from ws_f):
    // [0, 2BP)              mining: [0]=obj, [1]=c
    // [2BP, 2BP+1024)       best_prior: 512 ull (4 KiB)
    // [2BP+1024, +1280)     num_posS: 8 stripes x 32 ints (128B apart)
    // [2BP+1280, +1288)     acc: 8 floats ([3]=neg_obj, [4]=neg_c)
    // [2BP+1288]            n1_acc (int)
    // [2BP+2048, +4096)     accS: 64 stripes x 32 floats (128B apart)
    float* ws_f = (float*)d_ws;
    float* mining = ws_f;
    ull*   best_prior = (ull*)(ws_f + 2 * (size_t)BP);
    int*   num_posS = (int*)(ws_f + 2 * (size_t)BP + 1024);
    float* acc = ws_f + 2 * (size_t)BP + 1280;
    int*   n1_acc = (int*)(ws_f + 2 * (size_t)BP + 1288);
    float* accS = ws_f + 2 * (size_t)BP + 2048;

    // zero best_prior + num_posS + acc + n1 + accS in one shot (16 KiB)
    hipMemsetAsync((void*)best_prior, 0, 16384, stream);

    dim3 mg((PP + CHUNK - 1) / CHUNK, BB);
    k_match_a<<<mg, 256, 0, stream>>>(priors, truths, best_prior);

    k_ce<<<BP / 64, 256, 0, stream>>>(conf_data, obj_data, loc_data, priors,
                                      truths, labels, best_prior,
                                      mining /*obj*/, mining + BP /*c*/,
                                      num_posS, accS);

    k_select<<<64, 1024, 0, stream>>>(mining, num_posS, acc, n1_acc);

    k_final<<<1, 64, 0, stream>>>(acc, accS, num_posS, n1_acc, out);
}